// Round 5
// baseline (604.460 us; speedup 1.0000x reference)
//
#include <hip/hip_runtime.h>
#include <cstdint>
#include <cstddef>

#define THRESH   0.5f
#define NEGPOS   3
#define VAR0     0.1f
#define VAR1     0.2f
#define MAXO     64
#define NPRI     8
#define A1_T     256
#define ROW_T    1024
#define NBIN     4096
#define CAP      4096

// ---------------------------------------------------------------------------
// Kernel A1: per-(batch, prior-chunk) matching.
//  - per-prior best truth (strict > keeps first o == jnp.argmax axis=0),
//    emitted as code u8 = (best_ov >= THRESH) ? idx+1 : 0
//  - per-truth best prior: u64 key (iou_bits<<32 | ~p) -> max iou, ties ->
//    smallest p (== jnp.argmax axis=1 first-occurrence). Keys written to
//    PRIVATE per-chunk slots (plain stores, poison fully overwritten for
//    o<O) -- no device atomics, no workspace memset dispatch needed.
//  Pad priors (p>=P): box=0,area=1 -> iou==0 and larger p => lose all ties.
// ---------------------------------------------------------------------------
__global__ __launch_bounds__(A1_T)
void match_kernel(const float* __restrict__ priors,
                  const float* __restrict__ targets,
                  unsigned char* __restrict__ code,
                  unsigned long long* __restrict__ g_bp2,
                  int B, int P, int O, int chunks) {
    __shared__ float tx1[MAXO], ty1[MAXO], tx2[MAXO], ty2[MAXO], tarea[MAXO];
    __shared__ unsigned long long wkeys[(A1_T / 64) * MAXO];
    const int b   = blockIdx.x / chunks;
    const int ch  = blockIdx.x % chunks;
    const int tid = threadIdx.x;
    const int lane = tid & 63, wv = tid >> 6;

    if (tid < O) {
        const float* tr = targets + (size_t)(b * O + tid) * 5;
        float x1 = tr[0], y1 = tr[1], x2 = tr[2], y2 = tr[3];
        tx1[tid] = x1; ty1[tid] = y1; tx2[tid] = x2; ty2[tid] = y2;
        tarea[tid] = (x2 - x1) * (y2 - y1);
    }
    __syncthreads();

    float px1[NPRI], py1[NPRI], px2[NPRI], py2[NPRI], pa[NPRI], pov[NPRI];
    int   pidx[NPRI];
    const int p0 = ch * (A1_T * NPRI) + tid;
#pragma unroll
    for (int i = 0; i < NPRI; ++i) {
        int p = p0 + i * A1_T;
        pov[i] = -1.0f; pidx[i] = 0;
        px1[i] = 0.f; py1[i] = 0.f; px2[i] = 0.f; py2[i] = 0.f; pa[i] = 1.0f;
        if (p < P) {
            float4 pr = *(const float4*)(priors + (size_t)p * 4);
            px1[i] = pr.x - pr.z * 0.5f; py1[i] = pr.y - pr.w * 0.5f;
            px2[i] = pr.x + pr.z * 0.5f; py2[i] = pr.y + pr.w * 0.5f;
            pa[i]  = pr.z * pr.w;
        }
    }

    for (int o = 0; o < O; ++o) {
        float ax1 = tx1[o], ay1 = ty1[o], ax2 = tx2[o], ay2 = ty2[o], aa = tarea[o];
        float bo = -1.0f; unsigned bp = 0u;
#pragma unroll
        for (int i = 0; i < NPRI; ++i) {
            float lx = fmaxf(ax1, px1[i]), ly = fmaxf(ay1, py1[i]);
            float rx = fminf(ax2, px2[i]), ry = fminf(ay2, py2[i]);
            float w = fmaxf(rx - lx, 0.0f), h = fmaxf(ry - ly, 0.0f);
            float inter = w * h;
            float iou = __fdividef(inter, aa + pa[i] - inter);
            if (iou > pov[i]) { pov[i] = iou; pidx[i] = o; }      // first o wins
            if (iou > bo)     { bo = iou; bp = (unsigned)(p0 + i * A1_T); }
        }
        unsigned long long key =
            ((unsigned long long)__float_as_uint(bo) << 32) |
            (unsigned long long)(0xFFFFFFFFu - bp);
#pragma unroll
        for (int d = 1; d < 64; d <<= 1) {
            unsigned long long other = __shfl_xor(key, d, 64);
            if (other > key) key = other;
        }
        if (lane == 0) wkeys[wv * MAXO + o] = key;
    }
    __syncthreads();
    if (tid < O) {
        unsigned long long k = wkeys[tid];
#pragma unroll
        for (int w = 1; w < A1_T / 64; ++w) {
            unsigned long long o2 = wkeys[w * MAXO + tid];
            if (o2 > k) k = o2;
        }
        g_bp2[(size_t)(b * chunks + ch) * MAXO + tid] = k;
    }

#pragma unroll
    for (int i = 0; i < NPRI; ++i) {
        int p = p0 + i * A1_T;
        if (p < P)
            code[(size_t)b * P + p] =
                (pov[i] >= THRESH) ? (unsigned char)(pidx[i] + 1) : (unsigned char)0;
    }
}

// ---------------------------------------------------------------------------
// Kernel A2: forced-match patch, parallel. One block per batch; thread o
// reduces its key over chunks; LDS duplicate resolution gives exact
// last-truth-wins (== sequential .at[].set) without serialization.
// ---------------------------------------------------------------------------
__global__ __launch_bounds__(64)
void force_kernel(const unsigned long long* __restrict__ g_bp2,
                  unsigned char* __restrict__ code,
                  int P, int O, int chunks) {
    const int b = blockIdx.x, o = threadIdx.x;
    __shared__ unsigned s_p[MAXO];
    unsigned p = 0xFFFFFFFFu;
    if (o < O) {
        unsigned long long k = 0ull;
        for (int ch = 0; ch < chunks; ++ch) {
            unsigned long long v = g_bp2[(size_t)(b * chunks + ch) * MAXO + o];
            if (v > k) k = v;
        }
        p = 0xFFFFFFFFu - (unsigned)(k & 0xFFFFFFFFull);
        s_p[o] = p;
    }
    __syncthreads();
    if (o < O) {
        bool last = true;
        for (int o2 = o + 1; o2 < O; ++o2)
            if (s_p[o2] == p) { last = false; break; }
        if (last) code[(size_t)b * P + p] = (unsigned char)(o + 1);
    }
}

// ---------------------------------------------------------------------------
// Kernel B (fused ce+mine): one block per batch row, 1024 threads.
//  ph1: stream row -> mce value (LSE2-obj0 for negatives; identity: ce_c ==
//       ce_o there), 4096-linear-bin histogram (bin=min(4095,v*512), values
//       softplus in (0,~8) -> ~13/bin, no hot-bin atomics), LDS-compact
//       positives (block-scope atomics only!).
//  ph2: positives, one quarter-wave each: coalesced conf LSE + epilogue
//       (ce_c, ce_o, smooth-L1) on lane 0 of the quarter.
//  ph3: parallel suffix scan over bins -> boundary bin + rem for
//       k = min(3*npos, P-1).
//  ph4: re-stream row: sum bins>bound; compact boundary-bin candidates.
//  ph5: exact tie-aware top-rem among candidates (value-identical to
//       reference double-argsort sum; ties contribute equal values).
// Row results -> plain stores to rowout (visible to next kernel).
// ---------------------------------------------------------------------------
__global__ __launch_bounds__(ROW_T)
void row_kernel(const float* __restrict__ loc, const float* __restrict__ conf,
                const float* __restrict__ obj, const float* __restrict__ priors,
                const float* __restrict__ targets,
                const unsigned char* __restrict__ code,
                float* __restrict__ rowout, int P, int C, int O) {
    const int b = blockIdx.x;
    const int tid = threadIdx.x;
    const int lane = tid & 63, wv = tid >> 6;

    __shared__ unsigned hist[NBIN];
    __shared__ int s_idx[CAP];
    __shared__ int s_np, s_nc, s_bound, s_rem;
    __shared__ int wavetot[ROW_T / 64], wexc[ROW_T / 64];
    __shared__ float red[ROW_T / 64][4];

    for (int i = tid; i < NBIN; i += ROW_T) hist[i] = 0u;
    if (tid == 0) { s_np = 0; s_nc = 0; s_bound = NBIN; s_rem = 0; }
    __syncthreads();

    const size_t rowbase = (size_t)b * P;

    // ---- phase 1: stream, histogram, compact positives
    for (int i = tid; i < P; i += ROW_T) {
        unsigned cc = code[rowbase + i];
        float2 ob = *(const float2*)(obj + (rowbase + i) * 2);
        float m = fmaxf(ob.x, ob.y);
        float lse2 = m + __logf(__expf(ob.x - m) + __expf(ob.y - m));
        float v = 0.0f;
        if (cc == 0) {
            v = lse2 - ob.x;
        } else {
            int s = atomicAdd(&s_np, 1);
            if (s < CAP) s_idx[s] = (i << 8) | (int)cc;
        }
        int bin = (int)(v * 512.0f);
        bin = min(bin, NBIN - 1);
        atomicAdd(&hist[bin], 1u);
    }
    __syncthreads();
    const int np = s_np;

    float sl = 0.f, cec = 0.f, ceo = 0.f, neg = 0.f;

    // ---- phase 2: positives, quarter-wave per positive
    {
        const int unit = tid >> 4, lq = tid & 15;
        for (int j = unit; j < np; j += ROW_T / 16) {
            int pk = s_idx[j];
            int p  = pk >> 8, cc = pk & 0xFF;
            size_t t = rowbase + (size_t)p;
            const float* cr = conf + t * C;
            float s = 0.f;
            for (int c = lq; c < C; c += 16) s += __expf(cr[c]);
#pragma unroll
            for (int d = 1; d < 16; d <<= 1) s += __shfl_xor(s, d, 16);
            if (lq == 0) {
                const float* tr = targets + (size_t)(b * O + cc - 1) * 5;
                float2 ob = *(const float2*)(obj + t * 2);
                float m = fmaxf(ob.x, ob.y);
                float lse2 = m + __logf(__expf(ob.x - m) + __expf(ob.y - m));
                int lbl = (int)tr[4];
                cec += __logf(s) + lse2 - ob.y - cr[lbl];
                ceo += lse2 - ob.y;
                float4 pr = *(const float4*)(priors + (size_t)p * 4);
                float4 ld = *(const float4*)(loc + t * 4);
                float mx1 = tr[0], my1 = tr[1], mx2 = tr[2], my2 = tr[3];
                float gx  = ((mx1 + mx2) * 0.5f - pr.x) / (VAR0 * pr.z);
                float gy  = ((my1 + my2) * 0.5f - pr.y) / (VAR0 * pr.w);
                float gw2 = __logf((mx2 - mx1) / pr.z) / VAR1;
                float gh  = __logf((my2 - my1) / pr.w) / VAR1;
                float d0 = ld.x - gx,  a0 = fabsf(d0); sl += (a0 < 1.f) ? 0.5f*d0*d0 : a0 - 0.5f;
                float d1 = ld.y - gy,  a1 = fabsf(d1); sl += (a1 < 1.f) ? 0.5f*d1*d1 : a1 - 0.5f;
                float d2 = ld.z - gw2, a2 = fabsf(d2); sl += (a2 < 1.f) ? 0.5f*d2*d2 : a2 - 0.5f;
                float d3 = ld.w - gh,  a3 = fabsf(d3); sl += (a3 < 1.f) ? 0.5f*d3*d3 : a3 - 0.5f;
            }
        }
    }
    __syncthreads();   // s_idx reuse below

    // ---- phase 3: boundary via parallel suffix scan
    int k = NEGPOS * np;
    if (k > P - 1) k = P - 1;
    if (k > 0) {
        const int base = NBIN - 1 - 4 * tid;
        const int c0 = (int)hist[base],     c1 = (int)hist[base - 1];
        const int c2 = (int)hist[base - 2], c3 = (int)hist[base - 3];
        const int T = c0 + c1 + c2 + c3;
        int incl = T;
#pragma unroll
        for (int d = 1; d < 64; d <<= 1) {
            int vv = __shfl_up(incl, d, 64);
            if (lane >= d) incl += vv;
        }
        if (lane == 63) wavetot[wv] = incl;
        __syncthreads();
        if (wv == 0 && lane < ROW_T / 64) {
            int t2 = wavetot[lane], inc2 = t2;
#pragma unroll
            for (int d = 1; d < 16; d <<= 1) {
                int vv = __shfl_up(inc2, d, 16);
                if ((lane & 15) >= d) inc2 += vv;
            }
            wexc[lane] = inc2 - t2;
        }
        __syncthreads();
        const int E = wexc[wv] + incl - T;     // count in bins above my group
        if (E < k && E + T >= k) {             // boundary inside my 4 bins
            int bound, rem;
            if      (E + c0 >= k)           { bound = base;     rem = k - E; }
            else if (E + c0 + c1 >= k)      { bound = base - 1; rem = k - E - c0; }
            else if (E + c0 + c1 + c2 >= k) { bound = base - 2; rem = k - E - c0 - c1; }
            else                            { bound = base - 3; rem = k - E - c0 - c1 - c2; }
            s_bound = bound; s_rem = rem;
        }
    }
    __syncthreads();
    const int bound = s_bound, rem = s_rem;

    // ---- phase 4: sum above-boundary, compact boundary candidates
    if (k > 0) {
        for (int i = tid; i < P; i += ROW_T) {
            unsigned cc = code[rowbase + i];
            if (cc) continue;
            float2 ob = *(const float2*)(obj + (rowbase + i) * 2);
            float m = fmaxf(ob.x, ob.y);
            float v = m + __logf(__expf(ob.x - m) + __expf(ob.y - m)) - ob.x;
            int bin = (int)(v * 512.0f);
            bin = min(bin, NBIN - 1);
            if (bin > bound) {
                neg += v;
            } else if (bin == bound) {
                int c = atomicAdd(&s_nc, 1);
                if (c < CAP) s_idx[c] = __float_as_int(v);
            }
        }
    }
    __syncthreads();

    // ---- phase 5: exact top-rem among candidates (ties -> equal values,
    // sum identical to reference's stable-argsort choice)
    if (k > 0) {
        int n = s_nc; if (n > CAP) n = CAP;
        if (n <= rem) {
            for (int i = tid; i < n; i += ROW_T) neg += __int_as_float(s_idx[i]);
        } else {
            for (int i = tid; i < n; i += ROW_T) {
                unsigned bi = (unsigned)s_idx[i];
                int g = 0, e = 0;
                for (int j = 0; j < n; ++j) {
                    unsigned bj = (unsigned)s_idx[j];
                    g += (bj > bi);
                    e += (j < i && bj == bi);
                }
                if (g + e < rem) neg += __int_as_float((int)bi);
            }
        }
    }

    // ---- final block reduce + row output
#pragma unroll
    for (int d = 32; d > 0; d >>= 1) {
        sl  += __shfl_down(sl,  d, 64);
        cec += __shfl_down(cec, d, 64);
        ceo += __shfl_down(ceo, d, 64);
        neg += __shfl_down(neg, d, 64);
    }
    if (lane == 0) { red[wv][0] = sl; red[wv][1] = cec; red[wv][2] = ceo; red[wv][3] = neg; }
    __syncthreads();
    if (tid == 0) {
        float a0 = 0.f, a1 = 0.f, a2 = 0.f, a3 = 0.f;
        for (int w = 0; w < ROW_T / 64; ++w) {
            a0 += red[w][0]; a1 += red[w][1]; a2 += red[w][2]; a3 += red[w][3];
        }
        float* ro = rowout + (size_t)b * 8;
        ro[0] = (float)np; ro[1] = a0; ro[2] = a1; ro[3] = a2; ro[4] = a3;
    }
}

// ---------------------------------------------------------------------------
// Kernel D: final combine + divide by N. One wave.
// ---------------------------------------------------------------------------
__global__ __launch_bounds__(64)
void finish_kernel(const float* __restrict__ rowout,
                   float* __restrict__ out, int B) {
    const int lane = threadIdx.x;
    float npos = 0.f, sl = 0.f, cec = 0.f, ceo = 0.f, neg = 0.f;
    for (int b = lane; b < B; b += 64) {
        const float* ro = rowout + (size_t)b * 8;
        npos += ro[0]; sl += ro[1]; cec += ro[2]; ceo += ro[3]; neg += ro[4];
    }
#pragma unroll
    for (int d = 32; d > 0; d >>= 1) {
        npos += __shfl_down(npos, d, 64);
        sl   += __shfl_down(sl,   d, 64);
        cec  += __shfl_down(cec,  d, 64);
        ceo  += __shfl_down(ceo,  d, 64);
        neg  += __shfl_down(neg,  d, 64);
    }
    if (lane == 0) {
        out[0] = sl / npos;
        out[1] = (cec + neg) / npos;
        out[2] = (ceo + neg) / npos;
    }
}

extern "C" void kernel_launch(void* const* d_in, const int* in_sizes, int n_in,
                              void* d_out, int out_size, void* d_ws, size_t ws_size,
                              hipStream_t stream) {
    const float* loc     = (const float*)d_in[0];
    const float* conf    = (const float*)d_in[1];
    const float* obj     = (const float*)d_in[2];
    const float* priors  = (const float*)d_in[3];
    const float* targets = (const float*)d_in[4];

    const int P = in_sizes[3] / 4;
    const int B = in_sizes[0] / (4 * P);
    const int C = in_sizes[1] / (B * P);
    const int O = in_sizes[4] / (5 * B);

    const int chunks = (P + A1_T * NPRI - 1) / (A1_T * NPRI);

    char* ws = (char*)d_ws;
    size_t off = 0;
    unsigned long long* g_bp2 = (unsigned long long*)(ws + off);
    off += (size_t)B * chunks * MAXO * sizeof(unsigned long long);
    float* rowout = (float*)(ws + off);            off += (size_t)B * 8 * sizeof(float);
    unsigned char* code = (unsigned char*)(ws + off); off += (size_t)B * P;

    // no memset needed: every workspace word read downstream is written
    // unconditionally by an earlier kernel in this launch sequence.

    match_kernel<<<B * chunks, A1_T, 0, stream>>>(priors, targets, code, g_bp2,
                                                  B, P, O, chunks);
    force_kernel<<<B, 64, 0, stream>>>(g_bp2, code, P, O, chunks);
    row_kernel<<<B, ROW_T, 0, stream>>>(loc, conf, obj, priors, targets,
                                        code, rowout, P, C, O);
    finish_kernel<<<1, 64, 0, stream>>>(rowout, (float*)d_out, B);
}